// Round 2
// baseline (1063.513 us; speedup 1.0000x reference)
//
#include <hip/hip_runtime.h>
#include <hip/hip_bf16.h>

// LocalAttention: B=4, L=2048, C(d_model)=512, H=8, Dh=64.
// Round 2: fp32 I/O (reference dtype), fp32 compute, bf16 intermediates in ws.
//   gemm1x1   : Y[b,o,n] = sum_c W[o,c] * X[b,c,n] + bias[o]   (used 4x)
//   attn_fwd  : flash-style per (b,h,64-query-tile), online softmax
// Workspace (bf16): qh, kh, vh, ctx -> 4 * 8 MB = 32 MB.

#define BB  4
#define LL  2048
#define CC  512
#define HH  8
#define DHH 64

using bf16 = __hip_bfloat16;

__device__ __forceinline__ float ld(const float* p) { return *p; }
__device__ __forceinline__ float ld(const bf16* p) { return __bfloat162float(*p); }
__device__ __forceinline__ void  st(float* p, float v) { *p = v; }
__device__ __forceinline__ void  st(bf16* p, float v)  { *p = __float2bfloat16(v); }

// ---------------------------------------------------------------------------
// Pointwise (1x1 conv) GEMM: 64x64 output tile, BK=16, 256 threads, 4x4 micro.
// ---------------------------------------------------------------------------
template <typename TIn, typename TOut>
__global__ __launch_bounds__(256) void gemm1x1(const TIn* __restrict__ X,
                                               const float* __restrict__ W,
                                               const float* __restrict__ bias,
                                               TOut* __restrict__ Y)
{
    const int bt = blockIdx.z;
    const int o0 = blockIdx.y * 64;
    const int n0 = blockIdx.x * 64;
    const int t  = threadIdx.x;
    const int tx = t & 15, ty = t >> 4;

    __shared__ __align__(16) float As[16][68];  // As[k][m] = W[o0+m][k0+k]
    __shared__ __align__(16) float Bs[16][68];  // Bs[k][n] = X[bt][k0+k][n0+n]

    const TIn* Xb = X + (size_t)bt * CC * LL;
    float acc[4][4] = {};

    for (int k0 = 0; k0 < CC; k0 += 16) {
        #pragma unroll
        for (int idx = t; idx < 64 * 16; idx += 256) {   // W tile (coalesced in c)
            const int m = idx >> 4, kk = idx & 15;
            As[kk][m] = ld(&W[(size_t)(o0 + m) * CC + k0 + kk]);
        }
        #pragma unroll
        for (int idx = t; idx < 16 * 64; idx += 256) {   // X tile (coalesced in n)
            const int kk = idx >> 6, n = idx & 63;
            Bs[kk][n] = ld(&Xb[(size_t)(k0 + kk) * LL + n0 + n]);
        }
        __syncthreads();
        #pragma unroll
        for (int kk = 0; kk < 16; ++kk) {
            const float4 a = *(const float4*)&As[kk][ty * 4];
            const float4 b = *(const float4*)&Bs[kk][tx * 4];
            const float av[4] = {a.x, a.y, a.z, a.w};
            const float bv[4] = {b.x, b.y, b.z, b.w};
            #pragma unroll
            for (int i = 0; i < 4; ++i)
                #pragma unroll
                for (int j = 0; j < 4; ++j)
                    acc[i][j] += av[i] * bv[j];
        }
        __syncthreads();
    }

    #pragma unroll
    for (int i = 0; i < 4; ++i) {
        const int o = o0 + ty * 4 + i;
        const float bv = bias[o];
        #pragma unroll
        for (int j = 0; j < 4; ++j)
            st(&Y[(size_t)bt * CC * LL + (size_t)o * LL + n0 + tx * 4 + j],
               acc[i][j] + bv);
    }
}

// ---------------------------------------------------------------------------
// Flash attention. One workgroup = (b, h, 64-query tile). 256 threads.
// Layouts in LDS: Qs[d][q], Ks[d][n], Vt[n][d], Ps[n][q] (all padded to 68).
// scores[q,n] = 0.125 * sum_d Q[d,q] K[d,n]; masked -> -1e9; online softmax;
// O[d][q] += sum_n V[d,n] P[q,n].
// ---------------------------------------------------------------------------
__global__ __launch_bounds__(256) void attn_fwd(const bf16* __restrict__ qh,
                                                const bf16* __restrict__ kh,
                                                const bf16* __restrict__ vh,
                                                const float* __restrict__ mask,
                                                bf16* __restrict__ ctx)
{
    const int bh = blockIdx.y;            // 0..31
    const int b  = bh >> 3, h = bh & 7;
    const int l0 = blockIdx.x * 64;
    const int t  = threadIdx.x;
    const int tx = t & 15, ty = t >> 4;

    __shared__ __align__(16) float Qs[64][68];
    __shared__ __align__(16) float Ks[64][68];
    __shared__ __align__(16) float Vt[64][68];
    __shared__ __align__(16) float Ps[64][68];
    __shared__ float red[64][17];
    __shared__ float alphaS[64];
    __shared__ float lS[64];

    const size_t base = ((size_t)b * CC + h * DHH) * LL;  // channel h*64+d

    for (int idx = t; idx < 64 * 64; idx += 256) {
        const int d = idx >> 6, i = idx & 63;
        Qs[d][i] = ld(&qh[base + (size_t)d * LL + l0 + i]);
    }

    float m[4], l[4], O[4][4];
    #pragma unroll
    for (int i = 0; i < 4; ++i) {
        m[i] = -1e30f; l[i] = 0.f;
        #pragma unroll
        for (int j = 0; j < 4; ++j) O[i][j] = 0.f;
    }

    for (int n0 = 0; n0 < LL; n0 += 64) {
        __syncthreads();   // previous tile fully consumed before restaging
        for (int idx = t; idx < 64 * 64; idx += 256) {
            const int d = idx >> 6, n = idx & 63;
            Ks[d][n] = ld(&kh[base + (size_t)d * LL + n0 + n]);
            Vt[n][d] = ld(&vh[base + (size_t)d * LL + n0 + n]);
        }
        __syncthreads();

        // S = Q^T K  (thread: queries 4*ty.., keys 4*tx..)
        float s[4][4] = {};
        for (int d = 0; d < 64; ++d) {
            const float4 a  = *(const float4*)&Qs[d][ty * 4];
            const float4 bb = *(const float4*)&Ks[d][tx * 4];
            const float av[4]  = {a.x, a.y, a.z, a.w};
            const float bvv[4] = {bb.x, bb.y, bb.z, bb.w};
            #pragma unroll
            for (int i = 0; i < 4; ++i)
                #pragma unroll
                for (int j = 0; j < 4; ++j)
                    s[i][j] += av[i] * bvv[j];
        }
        #pragma unroll
        for (int j = 0; j < 4; ++j) {
            const float mv = mask[(size_t)b * LL + n0 + tx * 4 + j];
            const bool pad = (mv <= 0.5f);
            #pragma unroll
            for (int i = 0; i < 4; ++i)
                s[i][j] = pad ? -1e9f : s[i][j] * 0.125f;
        }

        // row-max partials across the 16 threads sharing each query row
        #pragma unroll
        for (int i = 0; i < 4; ++i) {
            red[ty * 4 + i][tx] =
                fmaxf(fmaxf(s[i][0], s[i][1]), fmaxf(s[i][2], s[i][3]));
        }
        __syncthreads();

        float newm[4], alpha[4], ps[4], p[4][4];
        #pragma unroll
        for (int i = 0; i < 4; ++i) {
            const int r = ty * 4 + i;
            float mx = m[i];
            for (int t2 = 0; t2 < 16; ++t2) mx = fmaxf(mx, red[r][t2]);
            newm[i]  = mx;
            alpha[i] = __expf(m[i] - mx);
            float sum = 0.f;
            #pragma unroll
            for (int j = 0; j < 4; ++j) {
                p[i][j] = __expf(s[i][j] - mx);
                sum += p[i][j];
                Ps[tx * 4 + j][r] = p[i][j];   // Ps[n][q]
            }
            ps[i] = sum;
            if (tx == 0) alphaS[r] = alpha[i];
        }
        __syncthreads();
        #pragma unroll
        for (int i = 0; i < 4; ++i) red[ty * 4 + i][tx] = ps[i];
        __syncthreads();
        #pragma unroll
        for (int i = 0; i < 4; ++i) {
            const int r = ty * 4 + i;
            float sum = 0.f;
            for (int t2 = 0; t2 < 16; ++t2) sum += red[r][t2];
            l[i] = l[i] * alpha[i] + sum;
            m[i] = newm[i];
        }

        // PV: thread holds O[d=4*ty+i][q=4*tx+j]
        float al[4];
        #pragma unroll
        for (int j = 0; j < 4; ++j) al[j] = alphaS[tx * 4 + j];
        #pragma unroll
        for (int i = 0; i < 4; ++i)
            #pragma unroll
            for (int j = 0; j < 4; ++j) O[i][j] *= al[j];
        for (int n = 0; n < 64; ++n) {
            const float4 vv = *(const float4*)&Vt[n][ty * 4];
            const float4 pp = *(const float4*)&Ps[n][tx * 4];
            const float va[4] = {vv.x, vv.y, vv.z, vv.w};
            const float pa[4] = {pp.x, pp.y, pp.z, pp.w};
            #pragma unroll
            for (int i = 0; i < 4; ++i)
                #pragma unroll
                for (int j = 0; j < 4; ++j)
                    O[i][j] += va[i] * pa[j];
        }
    }

    if (tx == 0) {
        #pragma unroll
        for (int i = 0; i < 4; ++i) lS[ty * 4 + i] = l[i];
    }
    __syncthreads();
    #pragma unroll
    for (int i = 0; i < 4; ++i) {
        const int d = ty * 4 + i;
        #pragma unroll
        for (int j = 0; j < 4; ++j)
            st(&ctx[base + (size_t)d * LL + l0 + tx * 4 + j],
               O[i][j] / lS[tx * 4 + j]);
    }
}

// ---------------------------------------------------------------------------
extern "C" void kernel_launch(void* const* d_in, const int* in_sizes, int n_in,
                              void* d_out, int out_size, void* d_ws, size_t ws_size,
                              hipStream_t stream)
{
    const float* q    = (const float*)d_in[0];
    const float* k    = (const float*)d_in[1];
    const float* v    = (const float*)d_in[2];
    const float* mask = (const float*)d_in[3];
    const float* Wq   = (const float*)d_in[4];
    const float* bq   = (const float*)d_in[5];
    const float* Wk   = (const float*)d_in[6];
    const float* bk   = (const float*)d_in[7];
    const float* Wv   = (const float*)d_in[8];
    const float* bv   = (const float*)d_in[9];
    const float* Wout = (const float*)d_in[10];
    const float* bout = (const float*)d_in[11];

    const size_t TSZ = (size_t)BB * CC * LL;   // 4,194,304 elements
    bf16* qh  = (bf16*)d_ws;
    bf16* kh  = qh + TSZ;
    bf16* vh  = kh + TSZ;
    bf16* ctx = vh + TSZ;

    dim3 gg(LL / 64, CC / 64, BB);
    gemm1x1<float, bf16><<<gg, 256, 0, stream>>>(q, Wq, bq, qh);
    gemm1x1<float, bf16><<<gg, 256, 0, stream>>>(k, Wk, bk, kh);
    gemm1x1<float, bf16><<<gg, 256, 0, stream>>>(v, Wv, bv, vh);
    attn_fwd<<<dim3(LL / 64, BB * HH), 256, 0, stream>>>(qh, kh, vh, mask, ctx);
    gemm1x1<bf16, float><<<gg, 256, 0, stream>>>(ctx, Wout, bout, (float*)d_out);
}

// Round 4
// 343.466 us; speedup vs baseline: 3.0964x; 3.0964x over previous
//
#include <hip/hip_runtime.h>
#include <hip/hip_bf16.h>

// LocalAttention B=4, L=2048, C=512, H=8, Dh=64 — round 4: MFMA rewrite
// (round-3 design; typedefs renamed to avoid HIP's built-in short4).
// Pipeline:
//   transpose_cvt : X fp32 [b][c][n] -> Xt bf16 [b][n][c]        (x3: q,k,v)
//   proj_gemm<0>  : Xt x W -> per-head position-major bf16 [bh][l][64] (q scaled 0.125, k)
//   proj_gemm<1>  : Xt x W -> channel-major bf16 [b][c][n]       (v)
//   attn_fwd      : S^T = K^T Q via mfma_32x32x16_bf16, online softmax in
//                   registers (q lives in lane index), P->LDS->PV^T MFMA,
//                   ctx bf16 [b][l][512]
//   proj_gemm<2>  : ctx x Wout -> fp32 [b][c][n]  (d_out)
// All LDS tiles: 64 bf16 k-columns per row = 8 x 16B blocks, XOR-swizzled
// (bk ^ swz(row)) -> conflict-free b128 access, no padding needed.

#define BB  4
#define LL  2048
#define CC  512
#define HH  8
#define DHH 64

typedef __attribute__((ext_vector_type(8)))  short bf16x8;   // 8 bf16 = 4 VGPR (MFMA A/B)
typedef __attribute__((ext_vector_type(4)))  short bf16x4;   // 8 B
typedef __attribute__((ext_vector_type(16))) float f32x16;   // MFMA C/D

__device__ __forceinline__ int swz(int r) { return (r + (r >> 3)) & 7; }

__device__ __forceinline__ unsigned short f2bu(float x) {   // fp32 -> bf16 bits (RNE)
    unsigned u = __float_as_uint(x);
    return (unsigned short)((u + 0x7FFFu + ((u >> 16) & 1u)) >> 16);
}
__device__ __forceinline__ float bu2f(unsigned short b) {
    return __uint_as_float(((unsigned)b) << 16);
}

// ---------------------------------------------------------------------------
// fp32 [b][c][n] -> bf16 [b][n][c]
// ---------------------------------------------------------------------------
__global__ __launch_bounds__(256) void transpose_cvt(const float* __restrict__ X,
                                                     unsigned short* __restrict__ Xt)
{
    const int b = blockIdx.z, c0 = blockIdx.y * 64, n0 = blockIdx.x * 64;
    const int t = threadIdx.x;
    __shared__ float T[64][65];

    const float* Xb = X + ((size_t)b * CC + c0) * LL + n0;
    #pragma unroll
    for (int i = 0; i < 4; ++i) {
        const int cl = (t >> 4) + 16 * i, nl = (t & 15) * 4;
        const float4 f = *(const float4*)(Xb + (size_t)cl * LL + nl);
        T[cl][nl + 0] = f.x; T[cl][nl + 1] = f.y;
        T[cl][nl + 2] = f.z; T[cl][nl + 3] = f.w;
    }
    __syncthreads();
    unsigned short* Ot = Xt + ((size_t)b * LL + n0) * CC + c0;
    #pragma unroll
    for (int i = 0; i < 2; ++i) {
        const int nl = (t >> 3) + 32 * i, cb = (t & 7) * 8;
        bf16x8 pk;
        #pragma unroll
        for (int j = 0; j < 8; ++j) pk[j] = (short)f2bu(T[cb + j][nl]);
        *(bf16x8*)(Ot + (size_t)nl * CC + cb) = pk;
    }
}

// ---------------------------------------------------------------------------
// GEMM: Y[b][o][n] = sum_c W[o][c] * Xt[b][n][c] + bias[o], 128x128 tile,
// BK=64, 4 waves of 64x64, mfma_f32_32x32x16_bf16.
// MODE 0: bf16 out, per-head position-major [b][h][n][64], value scaled
// MODE 1: bf16 out, channel-major [b][o][n]
// MODE 2: fp32 out, channel-major [b][o][n]
// ---------------------------------------------------------------------------
template <int MODE>
__global__ __launch_bounds__(256) void proj_gemm(const unsigned short* __restrict__ Xt,
                                                 const float* __restrict__ W,
                                                 const float* __restrict__ bias,
                                                 float scale,
                                                 void* __restrict__ Yv)
{
    const int b  = blockIdx.z, n0 = blockIdx.x * 128, m0 = blockIdx.y * 128;
    const int t  = threadIdx.x, lane = t & 63, wave = t >> 6;
    const int quad2 = lane >> 5, l31 = lane & 31;
    const int wm = (wave >> 1) * 64, wn = (wave & 1) * 64;

    __shared__ unsigned short As[128 * 64];   // [m][k] swizzled
    __shared__ unsigned short Bs[128 * 64];   // [n][k] swizzled
    __shared__ float biasS[128];

    f32x16 acc[2][2];
    #pragma unroll
    for (int i = 0; i < 2; ++i)
        #pragma unroll
        for (int j = 0; j < 2; ++j)
            #pragma unroll
            for (int e = 0; e < 16; ++e) acc[i][j][e] = 0.f;

    if (t < 128) biasS[t] = bias[m0 + t];

    const unsigned short* Xb = Xt + (size_t)b * LL * CC;

    for (int k0 = 0; k0 < CC; k0 += 64) {
        __syncthreads();
        // stage A: W fp32 -> bf16, 128 rows x 64 k
        #pragma unroll
        for (int i = 0; i < 8; ++i) {
            const int id = i * 256 + t;           // 2048 float4 chunks
            const int r = id >> 4, seg = id & 15; // seg: 16 float4 per row
            const float4 f = *(const float4*)(W + (size_t)(m0 + r) * CC + k0 + seg * 4);
            bf16x4 pk;
            pk[0] = (short)f2bu(f.x); pk[1] = (short)f2bu(f.y);
            pk[2] = (short)f2bu(f.z); pk[3] = (short)f2bu(f.w);
            const int bk = seg >> 1, lo = seg & 1;
            *(bf16x4*)(As + r * 64 + ((bk ^ swz(r)) * 8) + lo * 4) = pk;
        }
        // stage B: Xt bf16 direct copy, 128 rows x 64 k
        #pragma unroll
        for (int i = 0; i < 4; ++i) {
            const int id = i * 256 + t;           // 1024 16B chunks
            const int r = id >> 3, bk = id & 7;
            const bf16x8 v = *(const bf16x8*)(Xb + (size_t)(n0 + r) * CC + k0 + bk * 8);
            *(bf16x8*)(Bs + r * 64 + ((bk ^ swz(r)) * 8)) = v;
        }
        __syncthreads();
        #pragma unroll
        for (int ks = 0; ks < 4; ++ks) {
            bf16x8 af[2], bfr[2];
            #pragma unroll
            for (int mt = 0; mt < 2; ++mt) {
                const int r = wm + mt * 32 + l31, bk = quad2 + 2 * ks;
                af[mt] = *(const bf16x8*)(As + r * 64 + ((bk ^ swz(r)) * 8));
            }
            #pragma unroll
            for (int nt = 0; nt < 2; ++nt) {
                const int r = wn + nt * 32 + l31, bk = quad2 + 2 * ks;
                bfr[nt] = *(const bf16x8*)(Bs + r * 64 + ((bk ^ swz(r)) * 8));
            }
            #pragma unroll
            for (int mt = 0; mt < 2; ++mt)
                #pragma unroll
                for (int nt = 0; nt < 2; ++nt)
                    acc[mt][nt] = __builtin_amdgcn_mfma_f32_32x32x16_bf16(
                        af[mt], bfr[nt], acc[mt][nt], 0, 0, 0);
        }
    }

    // epilogue
    #pragma unroll
    for (int mt = 0; mt < 2; ++mt)
        #pragma unroll
        for (int nt = 0; nt < 2; ++nt) {
            const int nloc = wn + nt * 32 + l31;
            if (MODE == 0) {
                unsigned short* Y = (unsigned short*)Yv;
                #pragma unroll
                for (int rg2 = 0; rg2 < 4; ++rg2) {
                    const int rbase = wm + mt * 32 + 8 * rg2 + 4 * quad2;
                    bf16x4 pk;
                    #pragma unroll
                    for (int j = 0; j < 4; ++j) {
                        const float v = (acc[mt][nt][rg2 * 4 + j] + biasS[rbase + j]) * scale;
                        pk[j] = (short)f2bu(v);
                    }
                    const int mg = m0 + rbase;
                    const int h = mg >> 6, d = mg & 63;
                    *(bf16x4*)(Y + (((size_t)(b * HH + h) * LL) + n0 + nloc) * DHH + d) = pk;
                }
            } else {
                #pragma unroll
                for (int reg = 0; reg < 16; ++reg) {
                    const int row = (reg & 3) + 8 * (reg >> 2) + 4 * quad2;
                    const int mloc = wm + mt * 32 + row;
                    const float v = (acc[mt][nt][reg] + biasS[mloc]) * scale;
                    const size_t addr = ((size_t)b * CC + m0 + mloc) * LL + n0 + nloc;
                    if (MODE == 1) ((unsigned short*)Yv)[addr] = f2bu(v);
                    else           ((float*)Yv)[addr] = v;
                }
            }
        }
}

// ---------------------------------------------------------------------------
// Flash attention, MFMA. Block = 128 thr (2 waves), covers 128 queries.
// Wave computes S^T[64 n][64 q] = K^T Q (q pre-scaled), online softmax with
// q in the lane index, P^T -> LDS (bf16), O^T[64 d][64 q] += V * P^T.
// ---------------------------------------------------------------------------
__global__ __launch_bounds__(128, 1) void attn_fwd(
    const unsigned short* __restrict__ Qh,   // [b][h][l][64], pre-scaled by 0.125
    const unsigned short* __restrict__ Kh,   // [b][h][l][64]
    const unsigned short* __restrict__ Vh,   // [b][512][l] channel-major
    const float* __restrict__ mask,          // [b][1][L]
    unsigned short* __restrict__ ctx)        // [b][l][512]
{
    const int bh = blockIdx.x;               // 0..31 (fast index -> XCD K/V locality)
    const int b = bh >> 3, h = bh & 7;
    const int qb = blockIdx.y;               // 0..15
    const int t = threadIdx.x, lane = t & 63, wave = t >> 6;
    const int quad2 = lane >> 5, l31 = lane & 31;
    const int qbase = qb * 128 + wave * 64;

    __shared__ unsigned short Ks[64 * 64];   // [n][d] swizzled
    __shared__ unsigned short Vs[64 * 64];   // [d][n] swizzled
    __shared__ unsigned short Ps[2][64 * 64];// per-wave [q][n] swizzled
    __shared__ unsigned long long mw_s;

    // Q B-fragments, register-resident for the whole block
    const unsigned short* Qbase = Qh + (size_t)bh * LL * DHH;
    bf16x8 qf[2][4];
    #pragma unroll
    for (int qt = 0; qt < 2; ++qt)
        #pragma unroll
        for (int ks = 0; ks < 4; ++ks)
            qf[qt][ks] = *(const bf16x8*)(Qbase +
                (size_t)(qbase + qt * 32 + l31) * DHH + ks * 16 + quad2 * 8);

    f32x16 of[2][2];
    #pragma unroll
    for (int i = 0; i < 2; ++i)
        #pragma unroll
        for (int j = 0; j < 2; ++j)
            #pragma unroll
            for (int e = 0; e < 16; ++e) of[i][j][e] = 0.f;
    float m_run[2] = {-3e38f, -3e38f}, l_run[2] = {0.f, 0.f};

    const unsigned short* Kbase = Kh + (size_t)bh * LL * DHH;
    const unsigned short* Vbase = Vh + ((size_t)b * CC + h * DHH) * LL;
    const float* mb = mask + (size_t)b * LL;

    for (int n0 = 0; n0 < LL; n0 += 64) {
        __syncthreads();
        #pragma unroll
        for (int i = 0; i < 4; ++i) {        // Ks: 512 16B chunks
            const int id = i * 128 + t;
            const int r = id >> 3, bk = id & 7;
            const bf16x8 v = *(const bf16x8*)(Kbase + (size_t)(n0 + r) * DHH + bk * 8);
            *(bf16x8*)(Ks + r * 64 + ((bk ^ swz(r)) * 8)) = v;
        }
        #pragma unroll
        for (int i = 0; i < 4; ++i) {        // Vs
            const int id = i * 128 + t;
            const int r = id >> 3, bk = id & 7;
            const bf16x8 v = *(const bf16x8*)(Vbase + (size_t)r * LL + n0 + bk * 8);
            *(bf16x8*)(Vs + r * 64 + ((bk ^ swz(r)) * 8)) = v;
        }
        if (wave == 0) {
            const unsigned long long bal = __ballot(mb[n0 + lane] > 0.5f);
            if (lane == 0) mw_s = bal;
        }
        __syncthreads();
        const unsigned long long mw = mw_s;

        // S^T = K^T Q
        f32x16 sf[2][2];
        #pragma unroll
        for (int i = 0; i < 2; ++i)
            #pragma unroll
            for (int j = 0; j < 2; ++j)
                #pragma unroll
                for (int e = 0; e < 16; ++e) sf[i][j][e] = 0.f;
        #pragma unroll
        for (int ks = 0; ks < 4; ++ks) {
            bf16x8 af[2];
            #pragma unroll
            for (int mt = 0; mt < 2; ++mt) {
                const int r = mt * 32 + l31, bk = quad2 + 2 * ks;
                af[mt] = *(const bf16x8*)(Ks + r * 64 + ((bk ^ swz(r)) * 8));
            }
            #pragma unroll
            for (int mt = 0; mt < 2; ++mt)
                #pragma unroll
                for (int qt = 0; qt < 2; ++qt)
                    sf[mt][qt] = __builtin_amdgcn_mfma_f32_32x32x16_bf16(
                        af[mt], qf[qt][ks], sf[mt][qt], 0, 0, 0);
        }

        // online softmax (per q-tile; q == lane&31, rows are keys)
        #pragma unroll
        for (int qt = 0; qt < 2; ++qt) {
            float mx = -3e38f;
            #pragma unroll
            for (int mt = 0; mt < 2; ++mt)
                #pragma unroll
                for (int e = 0; e < 16; ++e) mx = fmaxf(mx, sf[mt][qt][e]);
            mx = fmaxf(mx, __shfl_xor(mx, 32, 64));
            const float mnew = fmaxf(m_run[qt], mx);
            const float alpha = __expf(m_run[qt] - mnew);
            float ps = 0.f;
            const int q = qt * 32 + l31;
            #pragma unroll
            for (int mt = 0; mt < 2; ++mt)
                #pragma unroll
                for (int rg2 = 0; rg2 < 4; ++rg2) {
                    bf16x4 pk;
                    #pragma unroll
                    for (int j = 0; j < 4; ++j) {
                        const int row = j + 8 * rg2 + 4 * quad2 + 32 * mt;
                        float p = __expf(sf[mt][qt][rg2 * 4 + j] - mnew);
                        p = ((mw >> row) & 1ull) ? p : 0.f;
                        const unsigned short pb = f2bu(p);
                        ps += bu2f(pb);           // sum what PV will actually use
                        pk[j] = (short)pb;
                    }
                    const int nbase = 32 * mt + 8 * rg2 + 4 * quad2;
                    const int bk = nbase >> 3;    // 4*mt + rg2
                    *(bf16x4*)(Ps[wave] + q * 64 + ((bk ^ swz(q)) * 8) + quad2 * 4) = pk;
                }
            ps += __shfl_xor(ps, 32, 64);
            l_run[qt] = l_run[qt] * alpha + ps;
            m_run[qt] = mnew;
            #pragma unroll
            for (int mt = 0; mt < 2; ++mt)
                #pragma unroll
                for (int e = 0; e < 16; ++e) of[mt][qt][e] *= alpha;
        }

        // O^T += V * P^T   (wave-private Ps: no barrier needed)
        #pragma unroll
        for (int ks = 0; ks < 4; ++ks) {
            bf16x8 vf[2], pf[2];
            #pragma unroll
            for (int mt = 0; mt < 2; ++mt) {
                const int r = mt * 32 + l31, bk = quad2 + 2 * ks;
                vf[mt] = *(const bf16x8*)(Vs + r * 64 + ((bk ^ swz(r)) * 8));
            }
            #pragma unroll
            for (int qt = 0; qt < 2; ++qt) {
                const int q = qt * 32 + l31, bk = quad2 + 2 * ks;
                pf[qt] = *(const bf16x8*)(Ps[wave] + q * 64 + ((bk ^ swz(q)) * 8));
            }
            #pragma unroll
            for (int mt = 0; mt < 2; ++mt)
                #pragma unroll
                for (int qt = 0; qt < 2; ++qt)
                    of[mt][qt] = __builtin_amdgcn_mfma_f32_32x32x16_bf16(
                        vf[mt], pf[qt], of[mt][qt], 0, 0, 0);
        }
    }

    // epilogue: ctx[b][l][h*64+d] = O^T[d][q] / l
    unsigned short* Cb = ctx + (size_t)b * LL * CC;
    #pragma unroll
    for (int qt = 0; qt < 2; ++qt) {
        const float inv = 1.0f / l_run[qt];
        const int q = qbase + qt * 32 + l31;
        #pragma unroll
        for (int mt = 0; mt < 2; ++mt)
            #pragma unroll
            for (int rg2 = 0; rg2 < 4; ++rg2) {
                bf16x4 pk;
                #pragma unroll
                for (int j = 0; j < 4; ++j)
                    pk[j] = (short)f2bu(of[mt][qt][rg2 * 4 + j] * inv);
                const int d = 32 * mt + 8 * rg2 + 4 * quad2;
                *(bf16x4*)(Cb + (size_t)q * CC + h * DHH + d) = pk;
            }
    }
}

// ---------------------------------------------------------------------------
extern "C" void kernel_launch(void* const* d_in, const int* in_sizes, int n_in,
                              void* d_out, int out_size, void* d_ws, size_t ws_size,
                              hipStream_t stream)
{
    const float* q    = (const float*)d_in[0];
    const float* k    = (const float*)d_in[1];
    const float* v    = (const float*)d_in[2];
    const float* mask = (const float*)d_in[3];
    const float* Wq   = (const float*)d_in[4];
    const float* bq   = (const float*)d_in[5];
    const float* Wk   = (const float*)d_in[6];
    const float* bk   = (const float*)d_in[7];
    const float* Wv   = (const float*)d_in[8];
    const float* bv   = (const float*)d_in[9];
    const float* Wout = (const float*)d_in[10];
    const float* bout = (const float*)d_in[11];

    const size_t TSZ = (size_t)BB * CC * LL;          // 4,194,304 elements
    unsigned short* Xt  = (unsigned short*)d_ws;      // 8 MB scratch (reused, then ctx)
    unsigned short* qh  = Xt + TSZ;
    unsigned short* kh  = qh + TSZ;
    unsigned short* vh  = kh + TSZ;
    unsigned short* ctx = Xt;                          // Xt dead after v-projection

    const dim3 tg(LL / 64, CC / 64, BB), tb(256);
    const dim3 gg(LL / 128, CC / 128, BB), gb(256);

    transpose_cvt<<<tg, tb, 0, stream>>>(q, Xt);
    proj_gemm<0><<<gg, gb, 0, stream>>>(Xt, Wq, bq, 0.125f, (void*)qh);
    transpose_cvt<<<tg, tb, 0, stream>>>(k, Xt);
    proj_gemm<0><<<gg, gb, 0, stream>>>(Xt, Wk, bk, 1.0f, (void*)kh);
    transpose_cvt<<<tg, tb, 0, stream>>>(v, Xt);
    proj_gemm<1><<<gg, gb, 0, stream>>>(Xt, Wv, bv, 1.0f, (void*)vh);

    attn_fwd<<<dim3(HH * BB, LL / 128), 128, 0, stream>>>(qh, kh, vh, mask, ctx);

    proj_gemm<2><<<gg, gb, 0, stream>>>(ctx, Wout, bout, 1.0f, d_out);
}

// Round 6
// 272.690 us; speedup vs baseline: 3.9001x; 1.2596x over previous
//
#include <hip/hip_runtime.h>
#include <hip/hip_bf16.h>

// LocalAttention B=4, L=2048, C=512, H=8, Dh=64 — round 6 (round-5 design,
// pk2 reimplemented without bit_cast of __hip_bfloat162).
// vs round 4: attn 4 waves x 32q (2 waves/SIMD), K/V double-buffer reg
// prefetch, log2-domain softmax (q pre-scaled 0.125*log2e), packed bf16
// conversion, precomputed mask ballots; proj retiled 64Mx128N (512 blocks).

#define BB  4
#define LL  2048
#define CC  512
#define HH  8
#define DHH 64

typedef __attribute__((ext_vector_type(8)))  short bf16x8;   // 16 B
typedef __attribute__((ext_vector_type(4)))  short bf16x4;   // 8 B
typedef __attribute__((ext_vector_type(16))) float f32x16;   // MFMA C/D
typedef __attribute__((ext_vector_type(2)))  unsigned uint2v;
typedef __attribute__((ext_vector_type(4)))  unsigned uint4v;

using us = unsigned short;

#if __has_builtin(__builtin_amdgcn_exp2f)
#define EXP2(x) __builtin_amdgcn_exp2f(x)
#else
#define EXP2(x) __expf(0.6931471805599453f * (x))
#endif

__device__ __forceinline__ int swz(int r) { return (r + (r >> 3)) & 7; }

__device__ __forceinline__ us f2bu(float x) {   // scalar fp32->bf16 (RNE)
    unsigned u = __float_as_uint(x);
    return (us)((u + 0x7FFFu + ((u >> 16) & 1u)) >> 16);
}
__device__ __forceinline__ unsigned pk2(float a, float b) {
    return (unsigned)f2bu(a) | ((unsigned)f2bu(b) << 16);
}
__device__ __forceinline__ bf16x4 pk4(float a, float b, float c, float d) {
    uint2v u; u[0] = pk2(a, b); u[1] = pk2(c, d);
    return __builtin_bit_cast(bf16x4, u);
}

// ---------------------------------------------------------------------------
// fp32 [b][c][n] -> bf16 [b][n][c]
// ---------------------------------------------------------------------------
__global__ __launch_bounds__(256) void transpose_cvt(const float* __restrict__ X,
                                                     us* __restrict__ Xt)
{
    const int b = blockIdx.z, c0 = blockIdx.y * 64, n0 = blockIdx.x * 64;
    const int t = threadIdx.x;
    __shared__ float T[64][65];

    const float* Xb = X + ((size_t)b * CC + c0) * LL + n0;
    #pragma unroll
    for (int i = 0; i < 4; ++i) {
        const int cl = (t >> 4) + 16 * i, nl = (t & 15) * 4;
        const float4 f = *(const float4*)(Xb + (size_t)cl * LL + nl);
        T[cl][nl + 0] = f.x; T[cl][nl + 1] = f.y;
        T[cl][nl + 2] = f.z; T[cl][nl + 3] = f.w;
    }
    __syncthreads();
    us* Ot = Xt + ((size_t)b * LL + n0) * CC + c0;
    #pragma unroll
    for (int i = 0; i < 2; ++i) {
        const int nl = (t >> 3) + 32 * i, cb = (t & 7) * 8;
        uint4v u;
        #pragma unroll
        for (int j = 0; j < 4; ++j)
            u[j] = pk2(T[cb + 2 * j][nl], T[cb + 2 * j + 1][nl]);
        *(bf16x8*)(Ot + (size_t)nl * CC + cb) = __builtin_bit_cast(bf16x8, u);
    }
}

// ---------------------------------------------------------------------------
// GEMM: Y[b][o][n] = sum_c W[o][c]*Xt[b][n][c] + bias[o].
// Block tile 64(M) x 128(N), BK=64, 256 thr = 4 waves of 32x64.
// MODE 0: bf16 out, per-head position-major [b][h][n][64], (acc+bias)*scale
// MODE 1: bf16 out, channel-major [b][o][n]
// MODE 2: fp32 out, channel-major [b][o][n]
// ---------------------------------------------------------------------------
template <int MODE>
__global__ __launch_bounds__(256, 2) void proj_gemm(const us* __restrict__ Xt,
                                                    const float* __restrict__ W,
                                                    const float* __restrict__ bias,
                                                    float scale,
                                                    void* __restrict__ Yv)
{
    const int b  = blockIdx.z, n0 = blockIdx.x * 128, m0 = blockIdx.y * 64;
    const int t  = threadIdx.x, lane = t & 63, wave = t >> 6;
    const int quad2 = lane >> 5, l31 = lane & 31;
    const int wm = (wave >> 1) * 32, wn = (wave & 1) * 64;

    __shared__ us As[64 * 64];    // [m][k] swizzled
    __shared__ us Bs[128 * 64];   // [n][k] swizzled
    __shared__ float biasS[64];

    f32x16 acc[2];
    #pragma unroll
    for (int nt = 0; nt < 2; ++nt)
        #pragma unroll
        for (int e = 0; e < 16; ++e) acc[nt][e] = 0.f;

    if (t < 64) biasS[t] = bias[m0 + t];

    const us* Xb = Xt + (size_t)b * LL * CC;

    for (int k0 = 0; k0 < CC; k0 += 64) {
        __syncthreads();
        // A: W fp32 -> bf16, 64 rows x 64 k (1024 float4 chunks)
        #pragma unroll
        for (int i = 0; i < 4; ++i) {
            const int id = i * 256 + t;
            const int r = id >> 4, seg = id & 15;
            const float4 f = *(const float4*)(W + (size_t)(m0 + r) * CC + k0 + seg * 4);
            const int bk = seg >> 1, lo = seg & 1;
            *(bf16x4*)(As + r * 64 + ((bk ^ swz(r)) * 8) + lo * 4) =
                pk4(f.x, f.y, f.z, f.w);
        }
        // B: Xt bf16 copy, 128 rows x 64 k (1024 16B chunks)
        #pragma unroll
        for (int i = 0; i < 4; ++i) {
            const int id = i * 256 + t;
            const int r = id >> 3, bk = id & 7;
            const bf16x8 v = *(const bf16x8*)(Xb + (size_t)(n0 + r) * CC + k0 + bk * 8);
            *(bf16x8*)(Bs + r * 64 + ((bk ^ swz(r)) * 8)) = v;
        }
        __syncthreads();
        #pragma unroll
        for (int ks = 0; ks < 4; ++ks) {
            const int bk = quad2 + 2 * ks;
            const int ra = wm + l31;
            const bf16x8 af = *(const bf16x8*)(As + ra * 64 + ((bk ^ swz(ra)) * 8));
            #pragma unroll
            for (int nt = 0; nt < 2; ++nt) {
                const int rb = wn + nt * 32 + l31;
                const bf16x8 bfr = *(const bf16x8*)(Bs + rb * 64 + ((bk ^ swz(rb)) * 8));
                acc[nt] = __builtin_amdgcn_mfma_f32_32x32x16_bf16(af, bfr, acc[nt], 0, 0, 0);
            }
        }
    }

    #pragma unroll
    for (int nt = 0; nt < 2; ++nt) {
        const int nloc = wn + nt * 32 + l31;
        if (MODE == 0) {
            us* Y = (us*)Yv;
            #pragma unroll
            for (int rg2 = 0; rg2 < 4; ++rg2) {
                const int rbase = wm + 8 * rg2 + 4 * quad2;
                float v0 = (acc[nt][rg2 * 4 + 0] + biasS[rbase + 0]) * scale;
                float v1 = (acc[nt][rg2 * 4 + 1] + biasS[rbase + 1]) * scale;
                float v2 = (acc[nt][rg2 * 4 + 2] + biasS[rbase + 2]) * scale;
                float v3 = (acc[nt][rg2 * 4 + 3] + biasS[rbase + 3]) * scale;
                const int mg = m0 + rbase;
                const int h = mg >> 6, d = mg & 63;
                *(bf16x4*)(Y + (((size_t)(b * HH + h) * LL) + n0 + nloc) * DHH + d) =
                    pk4(v0, v1, v2, v3);
            }
        } else {
            #pragma unroll
            for (int reg = 0; reg < 16; ++reg) {
                const int row = (reg & 3) + 8 * (reg >> 2) + 4 * quad2;
                const int mloc = wm + row;
                const float v = (acc[nt][reg] + biasS[mloc]) * scale;
                const size_t addr = ((size_t)b * CC + m0 + mloc) * LL + n0 + nloc;
                if (MODE == 1) ((us*)Yv)[addr] = f2bu(v);
                else           ((float*)Yv)[addr] = v;
            }
        }
    }
}

// ---------------------------------------------------------------------------
// Flash attention. Block = 256 thr (4 waves), each wave owns 32 queries.
// S^T[64 n][32 q] = K^T Q  (q pre-scaled by 0.125*log2e -> exp2 softmax),
// online softmax with q in the lane index, P^T -> wave-private LDS,
// O^T[64 d][32 q] += V P^T. K/V double-buffered with register prefetch.
// ---------------------------------------------------------------------------
__global__ __launch_bounds__(256, 2) void attn_fwd(
    const us* __restrict__ Qh,     // [b][h][l][64], pre-scaled
    const us* __restrict__ Kh,     // [b][h][l][64]
    const us* __restrict__ Vh,     // [b][512][l] channel-major
    const float* __restrict__ mask,// [b][1][L]
    us* __restrict__ ctx)          // [b][l][512]
{
    const int bh = blockIdx.x;     // 0..31
    const int b = bh >> 3, h = bh & 7;
    const int qb = blockIdx.y;     // 0..15
    const int t = threadIdx.x, lane = t & 63, wave = t >> 6;
    const int quad2 = lane >> 5, l31 = lane & 31;
    const int qg = qb * 128 + wave * 32;     // wave's query base

    __shared__ us Ks[2][64 * 64];  // [n][d] swizzled, double-buffered
    __shared__ us Vs[2][64 * 64];  // [d][n] swizzled
    __shared__ us Ps[4][32 * 64];  // per-wave [q][n] swizzled
    __shared__ unsigned long long mwS[32];

    const float* mb = mask + (size_t)b * LL;
    #pragma unroll
    for (int i = 0; i < 8; ++i) {            // precompute all mask ballots
        const int tile = wave * 8 + i;
        const unsigned long long bal = __ballot(mb[tile * 64 + lane] > 0.5f);
        if (lane == 0) mwS[tile] = bal;
    }

    // Q fragments (register-resident)
    const us* Qbase = Qh + (size_t)bh * LL * DHH;
    bf16x8 qf[4];
    #pragma unroll
    for (int ks = 0; ks < 4; ++ks)
        qf[ks] = *(const bf16x8*)(Qbase + (size_t)(qg + l31) * DHH + ks * 16 + quad2 * 8);

    f32x16 of[2];
    #pragma unroll
    for (int mt = 0; mt < 2; ++mt)
        #pragma unroll
        for (int e = 0; e < 16; ++e) of[mt][e] = 0.f;
    float m_run = -3e38f, l_run = 0.f;

    const us* Kbase = Kh + (size_t)bh * LL * DHH;
    const us* Vbase = Vh + ((size_t)b * CC + h * DHH) * LL;

    // stage tile 0 into buffer 0
    #pragma unroll
    for (int i = 0; i < 2; ++i) {
        const int id = i * 256 + t;
        const int r = id >> 3, bk = id & 7;
        *(bf16x8*)(Ks[0] + r * 64 + ((bk ^ swz(r)) * 8)) =
            *(const bf16x8*)(Kbase + (size_t)r * DHH + bk * 8);
        *(bf16x8*)(Vs[0] + r * 64 + ((bk ^ swz(r)) * 8)) =
            *(const bf16x8*)(Vbase + (size_t)r * LL + bk * 8);
    }
    __syncthreads();

    for (int it = 0; it < LL / 64; ++it) {
        const int cur = it & 1;

        // prefetch next K/V tile into registers
        bf16x8 kpre[2], vpre[2];
        if (it + 1 < LL / 64) {
            const int n1 = (it + 1) * 64;
            #pragma unroll
            for (int i = 0; i < 2; ++i) {
                const int id = i * 256 + t;
                const int r = id >> 3, bk = id & 7;
                kpre[i] = *(const bf16x8*)(Kbase + (size_t)(n1 + r) * DHH + bk * 8);
                vpre[i] = *(const bf16x8*)(Vbase + (size_t)r * LL + n1 + bk * 8);
            }
        }

        // S^T = K^T Q
        f32x16 sf[2];
        #pragma unroll
        for (int mt = 0; mt < 2; ++mt)
            #pragma unroll
            for (int e = 0; e < 16; ++e) sf[mt][e] = 0.f;
        #pragma unroll
        for (int ks = 0; ks < 4; ++ks) {
            const int bk = quad2 + 2 * ks;
            #pragma unroll
            for (int mt = 0; mt < 2; ++mt) {
                const int r = mt * 32 + l31;
                const bf16x8 af = *(const bf16x8*)(Ks[cur] + r * 64 + ((bk ^ swz(r)) * 8));
                sf[mt] = __builtin_amdgcn_mfma_f32_32x32x16_bf16(af, qf[ks], sf[mt], 0, 0, 0);
            }
        }

        // online softmax (scores in log2 units; q == l31, rows are keys)
        float mx = -3e38f;
        #pragma unroll
        for (int mt = 0; mt < 2; ++mt)
            #pragma unroll
            for (int e = 0; e < 16; ++e) mx = fmaxf(mx, sf[mt][e]);
        mx = fmaxf(mx, __shfl_xor(mx, 32, 64));
        const float mnew = fmaxf(m_run, mx);
        const float alpha = EXP2(m_run - mnew);
        const unsigned long long mw = mwS[it];
        float ps = 0.f;
        #pragma unroll
        for (int mt = 0; mt < 2; ++mt)
            #pragma unroll
            for (int rg2 = 0; rg2 < 4; ++rg2) {
                float p[4];
                #pragma unroll
                for (int j = 0; j < 4; ++j)
                    p[j] = EXP2(sf[mt][rg2 * 4 + j] - mnew);
                if (mw != 0xFFFFFFFFFFFFFFFFull) {
                    #pragma unroll
                    for (int j = 0; j < 4; ++j) {
                        const int row = 32 * mt + 8 * rg2 + 4 * quad2 + j;
                        p[j] = ((mw >> row) & 1ull) ? p[j] : 0.f;
                    }
                }
                ps += (p[0] + p[1]) + (p[2] + p[3]);
                const int bk = 4 * mt + rg2;
                *(bf16x4*)(Ps[wave] + l31 * 64 + ((bk ^ swz(l31)) * 8) + quad2 * 4) =
                    pk4(p[0], p[1], p[2], p[3]);
            }
        ps += __shfl_xor(ps, 32, 64);
        l_run = l_run * alpha + ps;
        m_run = mnew;
        #pragma unroll
        for (int mt = 0; mt < 2; ++mt)
            #pragma unroll
            for (int e = 0; e < 16; ++e) of[mt][e] *= alpha;

        // O^T += V P^T  (Ps wave-private: in-wave LDS ordering suffices)
        #pragma unroll
        for (int ks = 0; ks < 4; ++ks) {
            const int bk = quad2 + 2 * ks;
            const int rq = l31;
            const bf16x8 pf = *(const bf16x8*)(Ps[wave] + rq * 64 + ((bk ^ swz(rq)) * 8));
            #pragma unroll
            for (int mt = 0; mt < 2; ++mt) {
                const int r = mt * 32 + l31;
                const bf16x8 vf = *(const bf16x8*)(Vs[cur] + r * 64 + ((bk ^ swz(r)) * 8));
                of[mt] = __builtin_amdgcn_mfma_f32_32x32x16_bf16(vf, pf, of[mt], 0, 0, 0);
            }
        }

        // write prefetched tile to the alternate buffer
        if (it + 1 < LL / 64) {
            #pragma unroll
            for (int i = 0; i < 2; ++i) {
                const int id = i * 256 + t;
                const int r = id >> 3, bk = id & 7;
                *(bf16x8*)(Ks[1 - cur] + r * 64 + ((bk ^ swz(r)) * 8)) = kpre[i];
                *(bf16x8*)(Vs[1 - cur] + r * 64 + ((bk ^ swz(r)) * 8)) = vpre[i];
            }
        }
        __syncthreads();
    }

    // epilogue: ctx[b][q][h*64+d] = O^T[d][q] / l_run
    us* Cb = ctx + (size_t)b * LL * CC;
    const float inv = 1.0f / l_run;
    const int q = qg + l31;
    #pragma unroll
    for (int mt = 0; mt < 2; ++mt)
        #pragma unroll
        for (int rg2 = 0; rg2 < 4; ++rg2) {
            const int d = 32 * mt + 8 * rg2 + 4 * quad2;
            *(bf16x4*)(Cb + (size_t)q * CC + h * DHH + d) =
                pk4(of[mt][rg2 * 4 + 0] * inv, of[mt][rg2 * 4 + 1] * inv,
                    of[mt][rg2 * 4 + 2] * inv, of[mt][rg2 * 4 + 3] * inv);
        }
}

// ---------------------------------------------------------------------------
extern "C" void kernel_launch(void* const* d_in, const int* in_sizes, int n_in,
                              void* d_out, int out_size, void* d_ws, size_t ws_size,
                              hipStream_t stream)
{
    const float* q    = (const float*)d_in[0];
    const float* k    = (const float*)d_in[1];
    const float* v    = (const float*)d_in[2];
    const float* mask = (const float*)d_in[3];
    const float* Wq   = (const float*)d_in[4];
    const float* bq   = (const float*)d_in[5];
    const float* Wk   = (const float*)d_in[6];
    const float* bk   = (const float*)d_in[7];
    const float* Wv   = (const float*)d_in[8];
    const float* bv   = (const float*)d_in[9];
    const float* Wout = (const float*)d_in[10];
    const float* bout = (const float*)d_in[11];

    const size_t TSZ = (size_t)BB * CC * LL;   // 4,194,304 elements
    us* Xt  = (us*)d_ws;                        // 8 MB scratch (then ctx)
    us* qh  = Xt + TSZ;
    us* kh  = qh + TSZ;
    us* vh  = kh + TSZ;
    us* ctx = Xt;                               // Xt dead after v-projection

    const float SCALE_Q = 0.125f * 1.4426950408889634f;  // fold softmax scale+log2e

    const dim3 tg(LL / 64, CC / 64, BB), tb(256);
    const dim3 gg(LL / 128, CC / 64, BB), gb(256);

    transpose_cvt<<<tg, tb, 0, stream>>>(q, Xt);
    proj_gemm<0><<<gg, gb, 0, stream>>>(Xt, Wq, bq, SCALE_Q, (void*)qh);
    transpose_cvt<<<tg, tb, 0, stream>>>(k, Xt);
    proj_gemm<0><<<gg, gb, 0, stream>>>(Xt, Wk, bk, 1.0f, (void*)kh);
    transpose_cvt<<<tg, tb, 0, stream>>>(v, Xt);
    proj_gemm<1><<<gg, gb, 0, stream>>>(Xt, Wv, bv, 1.0f, (void*)vh);

    attn_fwd<<<dim3(HH * BB, LL / 128), 256, 0, stream>>>(qh, kh, vh, mask, ctx);

    proj_gemm<2><<<gg, gb, 0, stream>>>(ctx, Wout, bout, 1.0f, d_out);
}